// Round 7
// baseline (1824.641 us; speedup 1.0000x reference)
//
#include <hip/hip_runtime.h>
#include <hip/hip_bf16.h>
#include <math.h>

#define N_NODES 50000
#define N_EDGES 1600000
#define IN_DIM  128
#define HID     64
#define EPB     4096   // edges per sort block
#define NBLK    391    // ceil(N_EDGES / EPB)
#define NB16    3125   // buckets of 16 nodes (= agg blocks = GEMM tiles)
static constexpr float EPS = 1e-6f;

typedef __attribute__((ext_vector_type(8))) short          short8;   // 8 bf16
typedef __attribute__((ext_vector_type(4))) int            i32x4;
typedef __attribute__((ext_vector_type(4))) float          f32x4;
typedef __attribute__((ext_vector_type(2))) float          f32x2;

__device__ __forceinline__ unsigned short f2bf(float f) {   // round-nearest-even
    union { float f; unsigned int i; } c; c.f = f;
    unsigned int r = c.i + 0x7FFFu + ((c.i >> 16) & 1u);
    return (unsigned short)(r >> 16);
}
__device__ __forceinline__ unsigned char f2fp8(float f) {   // OCP e4m3, HW cvt
    int p = __builtin_amdgcn_cvt_pk_fp8_f32(f, f, 0, false);
    return (unsigned char)(p & 0xff);
}

// ==== weight packing =========================================================

template <int K>
__device__ __forceinline__ void pack_body(const float* __restrict__ wS,
                                          const float* __restrict__ wN,
                                          unsigned short* __restrict__ pS,
                                          unsigned short* __restrict__ pN, int blk) {
    constexpr int NSLOT = (K / 32) * 4 * 64;
    int slot = blk * 256 + (int)threadIdx.x;
    if (slot >= NSLOT) return;
    int lane = slot & 63;
    int ct   = slot >> 6;
    int t    = ct & 3;
    int c    = ct >> 2;
    int m    = lane & 15;
    int quad = lane >> 4;
    int col  = t * 16 + m;
#pragma unroll
    for (int j = 0; j < 8; ++j) {
        int k = c * 32 + quad * 8 + j;
        pS[slot * 8 + j] = f2bf(wS[k * 64 + col]);
        pN[slot * 8 + j] = f2bf(wN[k * 64 + col]);
    }
}

// ==== CSR-lite build: 16-node-bucket counting scatter ========================
// blockCounts layout is BUCKET-MAJOR: bc[b * NBLK + blk]  (scan reads contiguous)

// blocks 0..NBLK-1: per-block bucket histogram; blocks NBLK..NBLK+7: weight pack
__global__ __launch_bounds__(256) void bucket_count_pack(
    const int* __restrict__ ei, int* __restrict__ bc,
    const float* __restrict__ w0s, const float* __restrict__ w0n,
    const float* __restrict__ w1s, const float* __restrict__ w1n,
    const float* __restrict__ w2s, const float* __restrict__ w2n,
    unsigned short* __restrict__ p0S, unsigned short* __restrict__ p0N,
    unsigned short* __restrict__ p1S, unsigned short* __restrict__ p1N,
    unsigned short* __restrict__ p2S, unsigned short* __restrict__ p2N) {
    if (blockIdx.x >= NBLK) {
        int blk = blockIdx.x - NBLK;
        if (blk < 4)      pack_body<IN_DIM>(w0s, w0n, p0S, p0N, blk);
        else if (blk < 6) pack_body<HID>(w1s, w1n, p1S, p1N, blk - 4);
        else              pack_body<HID>(w2s, w2n, p2S, p2N, blk - 6);
        return;
    }
    __shared__ int hist[NB16];
    for (int i = threadIdx.x; i < NB16; i += 256) hist[i] = 0;
    __syncthreads();
    int base = blockIdx.x * EPB;
    int lim  = min(EPB, N_EDGES - base);
    for (int i = threadIdx.x; i < lim; i += 256)
        atomicAdd(&hist[ei[N_EDGES + base + i] >> 4], 1);
    __syncthreads();
    for (int b = threadIdx.x; b < NB16; b += 256)
        bc[(size_t)b * NBLK + blockIdx.x] = hist[b];
}

// ==== dual GEMM body (layer 0 only) ==========================================
template <int K, bool F32IN>
__device__ __forceinline__ void gemm_body(
    const void* __restrict__ Av,
    const unsigned short* __restrict__ pS,
    const unsigned short* __restrict__ pN,
    float* __restrict__ hs, unsigned char* __restrict__ hnq, int blk) {
    constexpr int NC = K / 32;
    int lane = threadIdx.x & 63;
    int wv   = threadIdx.x >> 6;
    int tile = blk * 4 + wv;
    if (tile >= N_NODES / 16) return;
    int m    = lane & 15;
    int quad = lane >> 4;

    const short8* pSf = (const short8*)pS;
    const short8* pNf = (const short8*)pN;

    f32x4 accS[4], accN[4];
#pragma unroll
    for (int t = 0; t < 4; ++t) {
        accS[t] = (f32x4){0.f, 0.f, 0.f, 0.f};
        accN[t] = (f32x4){0.f, 0.f, 0.f, 0.f};
    }
#pragma unroll
    for (int c = 0; c < NC; ++c) {
        short8 a;
        if constexpr (F32IN) {
            const float* Af = (const float*)Av + ((size_t)tile * 16 + m) * K + quad * 8 + c * 32;
            f32x4 a0 = *(const f32x4*)Af;
            f32x4 a1 = *(const f32x4*)(Af + 4);
#pragma unroll
            for (int k = 0; k < 4; ++k) a[k]     = (short)f2bf(a0[k]);
#pragma unroll
            for (int k = 0; k < 4; ++k) a[k + 4] = (short)f2bf(a1[k]);
        } else {
            const short8* Af = (const short8*)((const unsigned short*)Av +
                               ((size_t)tile * 16 + m) * K + quad * 8);
            a = Af[c * 4];
        }
#pragma unroll
        for (int t = 0; t < 4; ++t) {
            short8 bs = pSf[(c * 4 + t) * 64 + lane];
            short8 bn = pNf[(c * 4 + t) * 64 + lane];
            accS[t] = __builtin_amdgcn_mfma_f32_16x16x32_bf16(a, bs, accS[t], 0, 0, 0);
            accN[t] = __builtin_amdgcn_mfma_f32_16x16x32_bf16(a, bn, accN[t], 0, 0, 0);
        }
    }
    int row0 = tile * 16 + quad * 4;
#pragma unroll
    for (int t = 0; t < 4; ++t) {
#pragma unroll
        for (int r = 0; r < 4; ++r) {
            size_t o = (size_t)(row0 + r) * HID + t * 16 + m;
            hs[o]  = accS[t][r];
            hnq[o] = f2fp8(accN[t][r]);
        }
    }
}

// blocks 0..NB16-1: col_sum; blocks NB16.. : layer-0 GEMM (overlap)
__global__ __launch_bounds__(256) void col_sum_gemm0(
    const int* __restrict__ bc, int* __restrict__ totals,
    const float* __restrict__ x,
    const unsigned short* __restrict__ p0S, const unsigned short* __restrict__ p0N,
    float* __restrict__ hs, unsigned char* __restrict__ hnq) {
    if (blockIdx.x >= NB16) {
        gemm_body<IN_DIM, true>(x, p0S, p0N, hs, hnq, blockIdx.x - NB16);
        return;
    }
    __shared__ int ws[4];
    int b = blockIdx.x;
    int s = 0;
    for (int i = threadIdx.x; i < NBLK; i += 256) s += bc[(size_t)b * NBLK + i];
#pragma unroll
    for (int off = 32; off >= 1; off >>= 1) s += __shfl_xor(s, off, 64);
    if ((threadIdx.x & 63) == 0) ws[threadIdx.x >> 6] = s;
    __syncthreads();
    if (threadIdx.x == 0) totals[b] = ws[0] + ws[1] + ws[2] + ws[3];
}

// per-bucket: base prefix over totals + in-row exclusive scan over edge-blocks
__global__ __launch_bounds__(256) void col_fix_base(int* __restrict__ bc,
                                                    const int* __restrict__ totals,
                                                    int* __restrict__ bucketBase) {
    __shared__ int vals[NBLK];
    __shared__ int sbase;
    int b = blockIdx.x;
    for (int i = threadIdx.x; i < NBLK; i += 256) vals[i] = bc[(size_t)b * NBLK + i];
    if (threadIdx.x < 64) {   // wave 0: base_b = sum totals[0..b)
        int lane = threadIdx.x;
        int s = 0;
        for (int i = lane; i < b; i += 64) s += totals[i];
#pragma unroll
        for (int off = 32; off >= 1; off >>= 1) s += __shfl_xor(s, off, 64);
        if (lane == 0) {
            sbase = s;
            bucketBase[b] = s;
            if (b == NB16 - 1) bucketBase[NB16] = s + totals[b];   // == N_EDGES
        }
    }
    __syncthreads();
    if (threadIdx.x < 64) {
        int lane  = threadIdx.x;
        int carry = sbase;
        for (int base = 0; base < NBLK; base += 64) {
            int i = base + lane;
            int v = (i < NBLK) ? vals[i] : 0;
            int incl = v;
#pragma unroll
            for (int off = 1; off < 64; off <<= 1) {
                int t = __shfl_up(incl, off, 64);
                if (lane >= off) incl += t;
            }
            if (i < NBLK) vals[i] = carry + incl - v;
            carry += __shfl(incl, 63, 64);
        }
    }
    __syncthreads();
    for (int i = threadIdx.x; i < NBLK; i += 256) bc[(size_t)b * NBLK + i] = vals[i];
}

// scatter edges into bucket-grouped order, packed (src<<4)|(dst&15)
__global__ __launch_bounds__(256) void bucket_scatter(const int* __restrict__ ei,
                                                      const int* __restrict__ bc,
                                                      unsigned int* __restrict__ bucketPacked) {
    __shared__ int cur[NB16];
    for (int b = threadIdx.x; b < NB16; b += 256)
        cur[b] = bc[(size_t)b * NBLK + blockIdx.x];
    __syncthreads();
    int base = blockIdx.x * EPB;
    int lim  = min(EPB, N_EDGES - base);
    for (int i = threadIdx.x; i < lim; i += 256) {
        int s = ei[base + i];
        int d = ei[N_EDGES + base + i];
        int pos = atomicAdd(&cur[d >> 4], 1);
        bucketPacked[pos] = ((unsigned int)s << 4) | (unsigned int)(d & 15);
    }
}

// ==== edge-parallel gather-aggregate + update + fused GEMM / MLP head ========
// Block = one 16-node bucket (= one GEMM tile). 16 lane-groups (g = tid>>4)
// stride the bucket's edge list; lane r = tid&15 owns 4B of the 64B fp8 row.
// Accumulate into LDS acc[16][67] via ds_add_f32 (stride 67: conflict-spread).
// Zero divergence, coalesced packed-idx loads, no per-node sort needed.
// Degrees recomputed per layer via one predicated LDS atomic per edge.
template <bool MLP>
__global__ __launch_bounds__(256) void agg_update(
    const int* __restrict__ bucketBase, const unsigned int* __restrict__ bucketPacked,
    const unsigned char* __restrict__ hnq, const float* __restrict__ hs,
    const unsigned short* __restrict__ pS, const unsigned short* __restrict__ pN,
    float* __restrict__ hs2, unsigned char* __restrict__ hnq2,
    const float* __restrict__ mw1, const float* __restrict__ mb1,
    const float* __restrict__ mw2, const float* __restrict__ mb2,
    float* __restrict__ out) {
    __shared__ float accL[16 * 67];                    // stride 67: bank-spread
    __shared__ int   dcnt[16];
    __shared__ unsigned short sA[MLP ? 1 : 16 * 80];   // bf16 A-tile for fused GEMM
    __shared__ float sW1[MLP ? HID * 32 : 1];
    __shared__ float sW2[MLP ? 32 : 1];
    __shared__ float sB1[MLP ? 32 : 1];
    int tid = threadIdx.x;
    if (MLP) {
        for (int i = tid; i < HID * 32; i += 256) sW1[i] = mw1[i];
        if (tid < 32) { sW2[tid] = mw2[tid]; sB1[tid] = mb1[tid]; }
    }
    for (int i = tid; i < 16 * 67; i += 256) accL[i] = 0.f;
    if (tid < 16) dcnt[tid] = 0;
    __syncthreads();

    int b   = blockIdx.x;
    int beg = bucketBase[b];
    int n   = bucketBase[b + 1] - beg;
    int g   = tid >> 4;          // edge-stride lane-group 0..15
    int r   = tid & 15;          // 4B chunk of the 64B row
    const unsigned int* pk = bucketPacked + beg;
    const unsigned char* hb_ = hnq + r * 4;

#pragma unroll 2
    for (int i = g; i < n; i += 16) {
        unsigned p    = pk[i];           // 16 lanes same addr -> merged
        unsigned src  = p >> 4;
        unsigned slot = p & 15u;
        unsigned w = *(const unsigned*)(hb_ + (src << 6));
        if (r == 0) atomicAdd(&dcnt[slot], 1);
        float* ap = &accL[slot * 67 + r * 4];
#if __has_builtin(__builtin_amdgcn_cvt_pk_f32_fp8)
        f32x2 lo = __builtin_amdgcn_cvt_pk_f32_fp8((int)w, false);
        f32x2 hi = __builtin_amdgcn_cvt_pk_f32_fp8((int)w, true);
        atomicAdd(ap + 0, lo[0]); atomicAdd(ap + 1, lo[1]);
        atomicAdd(ap + 2, hi[0]); atomicAdd(ap + 3, hi[1]);
#else
        atomicAdd(ap + 0, __builtin_amdgcn_cvt_f32_fp8((int)w, 0));
        atomicAdd(ap + 1, __builtin_amdgcn_cvt_f32_fp8((int)w, 1));
        atomicAdd(ap + 2, __builtin_amdgcn_cvt_f32_fp8((int)w, 2));
        atomicAdd(ap + 3, __builtin_amdgcn_cvt_f32_fp8((int)w, 3));
#endif
    }
    __syncthreads();

    int sn   = g;                 // node slot within tile
    int node = b * 16 + sn;
    float acc[4];
#pragma unroll
    for (int k = 0; k < 4; ++k) acc[k] = accL[sn * 67 + r * 4 + k];
    int dg = dcnt[sn];
    float invdeg = 1.0f / fmaxf((float)dg, 1.0f);
    f32x4 h = *(const f32x4*)(hs + (size_t)node * HID + r * 4);
    float v[4], ss = 0.f;
#pragma unroll
    for (int k = 0; k < 4; ++k) {
        v[k] = fmaxf(fmaf(acc[k], invdeg, h[k]), 0.f);
        ss += v[k] * v[k];
    }
    // reduce across the 16 r-lanes of this node (masks 1,2,4,8)
    ss += __shfl_xor(ss, 1, 64);
    ss += __shfl_xor(ss, 2, 64);
    ss += __shfl_xor(ss, 4, 64);
    ss += __shfl_xor(ss, 8, 64);
    float rs = 1.0f / (sqrtf(ss) + EPS);

    if constexpr (!MLP) {
        // stage normalized row as bf16 (A-operand of the fused dual GEMM)
        unsigned short* ap = &sA[sn * 80 + r * 4];
#pragma unroll
        for (int k = 0; k < 4; ++k) ap[k] = f2bf(v[k] * rs);
        __syncthreads();
        int lane = tid & 63;
        int wv_  = tid >> 6;
        int m    = lane & 15;
        int quad = lane >> 4;
        const short8* pB = (const short8*)((wv_ < 2) ? pS : pN);
        int t0 = (wv_ & 1) * 2;
        f32x4 gacc[2];
        gacc[0] = (f32x4){0.f, 0.f, 0.f, 0.f};
        gacc[1] = (f32x4){0.f, 0.f, 0.f, 0.f};
#pragma unroll
        for (int c = 0; c < 2; ++c) {
            short8 a = *(const short8*)&sA[m * 80 + quad * 8 + c * 32];
#pragma unroll
            for (int tt = 0; tt < 2; ++tt) {
                short8 bb = pB[(c * 4 + t0 + tt) * 64 + lane];
                gacc[tt] = __builtin_amdgcn_mfma_f32_16x16x32_bf16(a, bb, gacc[tt], 0, 0, 0);
            }
        }
        int row0 = b * 16 + quad * 4;
#pragma unroll
        for (int tt = 0; tt < 2; ++tt) {
            int col = (t0 + tt) * 16 + m;
#pragma unroll
            for (int rr = 0; rr < 4; ++rr) {
                size_t o = (size_t)(row0 + rr) * HID + col;
                if (wv_ < 2) hs2[o]  = gacc[tt][rr];
                else         hnq2[o] = f2fp8(gacc[tt][rr]);
            }
        }
    } else {
        // write normalized row back into accL, then 16 threads x 2 cols MLP
#pragma unroll
        for (int k = 0; k < 4; ++k) accL[sn * 67 + r * 4 + k] = v[k] * rs;
        __syncthreads();
        int c0 = r * 2;
        float y0 = sB1[c0], y1 = sB1[c0 + 1];
        const float* hrow = &accL[sn * 67];
#pragma unroll 8
        for (int k = 0; k < HID; ++k) {
            float hv = hrow[k];
            y0 = fmaf(hv, sW1[k * 32 + c0], y0);
            y1 = fmaf(hv, sW1[k * 32 + c0 + 1], y1);
        }
        float p = fmaxf(y0, 0.f) * sW2[c0] + fmaxf(y1, 0.f) * sW2[c0 + 1];
        p += __shfl_xor(p, 1, 64);
        p += __shfl_xor(p, 2, 64);
        p += __shfl_xor(p, 4, 64);
        p += __shfl_xor(p, 8, 64);
        if (r == 0) out[node] = 1.0f / (1.0f + __expf(-(p + mb2[0])));
    }
}

extern "C" void kernel_launch(void* const* d_in, const int* in_sizes, int n_in,
                              void* d_out, int out_size, void* d_ws, size_t ws_size,
                              hipStream_t stream) {
    const float* x   = (const float*)d_in[0];
    const int*   ei  = (const int*)d_in[1];
    const float* w0s = (const float*)d_in[2];
    const float* w0n = (const float*)d_in[3];
    const float* w1s = (const float*)d_in[4];
    const float* w1n = (const float*)d_in[5];
    const float* w2s = (const float*)d_in[6];
    const float* w2n = (const float*)d_in[7];
    const float* mw1 = (const float*)d_in[8];
    const float* mb1 = (const float*)d_in[9];
    const float* mw2 = (const float*)d_in[10];
    const float* mb2 = (const float*)d_in[11];
    float*       out = (float*)d_out;

    // ---- workspace layout (sections multiple of 256 ints) ----
    int* bc          = (int*)d_ws;               // NB16*NBLK = 1,221,875 (pad 1,222,144)
    int* totals      = bc + 1222144;             // 3200
    int* bucketBase  = totals + 3200;            // 3200 (needs NB16+1)
    unsigned int* bucketPacked = (unsigned int*)(bucketBase + 3200);   // N_EDGES
    const size_t NH = (size_t)N_NODES * HID;
    float*          hsA  = (float*)(bucketPacked + N_EDGES);      // NH f32
    unsigned char*  hnqA = (unsigned char*)(hsA + NH);            // NH fp8
    float*          hsB  = (float*)(hnqA + NH);                   // NH f32
    unsigned char*  hnqB = (unsigned char*)(hsB + NH);            // NH fp8
    unsigned short* p0S = (unsigned short*)(hnqB + NH);           // 128*64
    unsigned short* p0N = p0S + IN_DIM * HID;
    unsigned short* p1S = p0N + IN_DIM * HID;    // 64*64
    unsigned short* p1N = p1S + HID * HID;
    unsigned short* p2S = p1N + HID * HID;
    unsigned short* p2N = p2S + HID * HID;
    // total ~43 MB

    const int gemmGrid = (N_NODES / 16 + 3) / 4; // 782 (layer-0 GEMM only)

    // ---- CSR-lite build + weight pack + layer-0 GEMM ----
    bucket_count_pack<<<NBLK + 8, 256, 0, stream>>>(
        ei, bc, w0s, w0n, w1s, w1n, w2s, w2n,
        p0S, p0N, p1S, p1N, p2S, p2N);
    col_sum_gemm0<<<NB16 + gemmGrid, 256, 0, stream>>>(
        bc, totals, x, p0S, p0N, hsA, hnqA);
    col_fix_base<<<NB16, 256, 0, stream>>>(bc, totals, bucketBase);
    bucket_scatter<<<NBLK, 256, 0, stream>>>(ei, bc, bucketPacked);

    // ---- layer 0 aggregate + fused layer-1 GEMM ----
    agg_update<false><<<NB16, 256, 0, stream>>>(
        bucketBase, bucketPacked, hnqA, hsA, p1S, p1N, hsB, hnqB,
        nullptr, nullptr, nullptr, nullptr, nullptr);

    // ---- layer 1 aggregate + fused layer-2 GEMM ----
    agg_update<false><<<NB16, 256, 0, stream>>>(
        bucketBase, bucketPacked, hnqB, hsB, p2S, p2N, hsA, hnqA,
        nullptr, nullptr, nullptr, nullptr, nullptr);

    // ---- layer 2 aggregate + fused MLP head ----
    agg_update<true><<<NB16, 256, 0, stream>>>(
        bucketBase, bucketPacked, hnqA, hsA, nullptr, nullptr, nullptr, nullptr,
        mw1, mb1, mw2, mb2, out);
}

// Round 8
// 360.289 us; speedup vs baseline: 5.0644x; 5.0644x over previous
//
#include <hip/hip_runtime.h>
#include <hip/hip_bf16.h>
#include <math.h>

#define N_NODES 50000
#define N_EDGES 1600000
#define IN_DIM  128
#define HID     64
#define CBLK    1024   // blocks for edge-stride kernels (count / scatter)
#define SBLK    196    // blocks covering 50048 nodes for the scan
static constexpr float EPS = 1e-6f;

typedef __attribute__((ext_vector_type(8))) short          short8;   // 8 bf16
typedef __attribute__((ext_vector_type(4))) int            i32x4;
typedef __attribute__((ext_vector_type(4))) float          f32x4;
typedef __attribute__((ext_vector_type(2))) float          f32x2;

__device__ __forceinline__ unsigned short f2bf(float f) {   // round-nearest-even
    union { float f; unsigned int i; } c; c.f = f;
    unsigned int r = c.i + 0x7FFFu + ((c.i >> 16) & 1u);
    return (unsigned short)(r >> 16);
}
__device__ __forceinline__ unsigned char f2fp8(float f) {   // OCP e4m3, HW cvt
    int p = __builtin_amdgcn_cvt_pk_fp8_f32(f, f, 0, false);
    return (unsigned char)(p & 0xff);
}

// ==== weight packing =========================================================

template <int K>
__device__ __forceinline__ void pack_body(const float* __restrict__ wS,
                                          const float* __restrict__ wN,
                                          unsigned short* __restrict__ pS,
                                          unsigned short* __restrict__ pN, int blk) {
    constexpr int NSLOT = (K / 32) * 4 * 64;
    int slot = blk * 256 + (int)threadIdx.x;
    if (slot >= NSLOT) return;
    int lane = slot & 63;
    int ct   = slot >> 6;
    int t    = ct & 3;
    int c    = ct >> 2;
    int m    = lane & 15;
    int quad = lane >> 4;
    int col  = t * 16 + m;
#pragma unroll
    for (int j = 0; j < 8; ++j) {
        int k = c * 32 + quad * 8 + j;
        pS[slot * 8 + j] = f2bf(wS[k * 64 + col]);
        pN[slot * 8 + j] = f2bf(wN[k * 64 + col]);
    }
}

// ==== build step 0: zero degree array + global allocator =====================
__global__ __launch_bounds__(256) void zero_ws(int* __restrict__ z) {
    int i = blockIdx.x * 256 + threadIdx.x;
    if (i < 50112) z[i] = 0;
}

// ==== build step 1: degree count (global atomics) + weight pack ==============
// blocks 0..CBLK-1: edge-stride degree count; blocks CBLK..CBLK+7: weight pack
// (pack blk 7 also zeroes the sentinel rows at hnqA/hnqB[N_NODES])
__global__ __launch_bounds__(256) void count_pack(
    const int* __restrict__ ei, int* __restrict__ deg,
    const float* __restrict__ w0s, const float* __restrict__ w0n,
    const float* __restrict__ w1s, const float* __restrict__ w1n,
    const float* __restrict__ w2s, const float* __restrict__ w2n,
    unsigned short* __restrict__ p0S, unsigned short* __restrict__ p0N,
    unsigned short* __restrict__ p1S, unsigned short* __restrict__ p1N,
    unsigned short* __restrict__ p2S, unsigned short* __restrict__ p2N,
    unsigned char* __restrict__ hnqA, unsigned char* __restrict__ hnqB) {
    if (blockIdx.x >= CBLK) {
        int blk = blockIdx.x - CBLK;
        if (blk == 7) {
            if (threadIdx.x >= 128 && threadIdx.x < 144)
                ((unsigned int*)(hnqA + (size_t)N_NODES * HID))[threadIdx.x - 128] = 0u;
            if (threadIdx.x >= 144 && threadIdx.x < 160)
                ((unsigned int*)(hnqB + (size_t)N_NODES * HID))[threadIdx.x - 144] = 0u;
        }
        if (blk < 4)      pack_body<IN_DIM>(w0s, w0n, p0S, p0N, blk);
        else if (blk < 6) pack_body<HID>(w1s, w1n, p1S, p1N, blk - 4);
        else              pack_body<HID>(w2s, w2n, p2S, p2N, blk - 6);
        return;
    }
    for (int i = blockIdx.x * 256 + threadIdx.x; i < N_EDGES; i += CBLK * 256)
        atomicAdd(&deg[ei[N_EDGES + i]], 1);
}

// ==== dual GEMM body (layer 0 only) ==========================================
template <int K, bool F32IN>
__device__ __forceinline__ void gemm_body(
    const void* __restrict__ Av,
    const unsigned short* __restrict__ pS,
    const unsigned short* __restrict__ pN,
    float* __restrict__ hs, unsigned char* __restrict__ hnq, int blk) {
    constexpr int NC = K / 32;
    int lane = threadIdx.x & 63;
    int wv   = threadIdx.x >> 6;
    int tile = blk * 4 + wv;
    if (tile >= N_NODES / 16) return;
    int m    = lane & 15;
    int quad = lane >> 4;

    const short8* pSf = (const short8*)pS;
    const short8* pNf = (const short8*)pN;

    f32x4 accS[4], accN[4];
#pragma unroll
    for (int t = 0; t < 4; ++t) {
        accS[t] = (f32x4){0.f, 0.f, 0.f, 0.f};
        accN[t] = (f32x4){0.f, 0.f, 0.f, 0.f};
    }
#pragma unroll
    for (int c = 0; c < NC; ++c) {
        short8 a;
        if constexpr (F32IN) {
            const float* Af = (const float*)Av + ((size_t)tile * 16 + m) * K + quad * 8 + c * 32;
            f32x4 a0 = *(const f32x4*)Af;
            f32x4 a1 = *(const f32x4*)(Af + 4);
#pragma unroll
            for (int k = 0; k < 4; ++k) a[k]     = (short)f2bf(a0[k]);
#pragma unroll
            for (int k = 0; k < 4; ++k) a[k + 4] = (short)f2bf(a1[k]);
        } else {
            const short8* Af = (const short8*)((const unsigned short*)Av +
                               ((size_t)tile * 16 + m) * K + quad * 8);
            a = Af[c * 4];
        }
#pragma unroll
        for (int t = 0; t < 4; ++t) {
            short8 bs = pSf[(c * 4 + t) * 64 + lane];
            short8 bn = pNf[(c * 4 + t) * 64 + lane];
            accS[t] = __builtin_amdgcn_mfma_f32_16x16x32_bf16(a, bs, accS[t], 0, 0, 0);
            accN[t] = __builtin_amdgcn_mfma_f32_16x16x32_bf16(a, bn, accN[t], 0, 0, 0);
        }
    }
    int row0 = tile * 16 + quad * 4;
#pragma unroll
    for (int t = 0; t < 4; ++t) {
#pragma unroll
        for (int r = 0; r < 4; ++r) {
            size_t o = (size_t)(row0 + r) * HID + t * 16 + m;
            hs[o]  = accS[t][r];
            hnq[o] = f2fp8(accN[t][r]);
        }
    }
}

// ==== build step 2: order-free segment allocation + sentinels; + layer-0 GEMM
// blocks 0..SBLK-1: per-wave padded-degree sum -> ONE atomicAdd on gcount per
// wave -> in-wave prefix gives pbeg (all multiples of 8). Sentinel-fill pads.
// blocks SBLK.. : layer-0 GEMM (independent, overlapped).
__global__ __launch_bounds__(256) void scan_gemm0(
    const int* __restrict__ deg, int* __restrict__ pbeg, int* __restrict__ cursor,
    int* __restrict__ csr, int* __restrict__ gcount,
    const float* __restrict__ x,
    const unsigned short* __restrict__ p0S, const unsigned short* __restrict__ p0N,
    float* __restrict__ hs, unsigned char* __restrict__ hnq) {
    if (blockIdx.x >= SBLK) {
        gemm_body<IN_DIM, true>(x, p0S, p0N, hs, hnq, blockIdx.x - SBLK);
        return;
    }
    int node = blockIdx.x * 256 + threadIdx.x;
    int lane = threadIdx.x & 63;
    int d  = (node < N_NODES) ? deg[node] : 0;
    int vp = (d + 7) & ~7;
    int incl = vp;
#pragma unroll
    for (int off = 1; off < 64; off <<= 1) {
        int t = __shfl_up(incl, off, 64);
        if (lane >= off) incl += t;
    }
    int pos = 0;
    if (lane == 63) pos = atomicAdd(gcount, incl);
    pos = __shfl(pos, 63, 64);
    int pb = pos + incl - vp;
    if (node < N_NODES) {
        pbeg[node]   = pb;
        cursor[node] = pb;
        for (int j = d; j < vp; ++j) csr[pb + j] = N_NODES;   // sentinels
    }
}

// ==== build step 3: scatter edges into per-node segments =====================
__global__ __launch_bounds__(256) void scatter_csr(const int* __restrict__ ei,
                                                   int* __restrict__ cursor,
                                                   int* __restrict__ csr) {
    for (int i = blockIdx.x * 256 + threadIdx.x; i < N_EDGES; i += CBLK * 256) {
        int s = ei[i];
        int d = ei[N_EDGES + i];
        int pos = atomicAdd(&cursor[d], 1);
        csr[pos] = s;
    }
}

// ==== fused gather-aggregate + update + NEXT-LAYER dual GEMM (or MLP head) ===
// Round-12 proven shape: 4 nodes per wave, 16 lanes per node (sn = tid>>4,
// r = lane&15 -> 4B chunk). Maskless main loop (padded CSR w/ sentinels).
// !MLP: block's 16 nodes = one GEMM tile; normalized bf16 rows staged in LDS
// then 4 waves compute the dual MFMA GEMM -> next layer's hs2/hnq2.
template <bool MLP>
__global__ __launch_bounds__(256) void agg_update(
    const int* __restrict__ pbeg, const int* __restrict__ rdeg,
    const int* __restrict__ csr,
    const unsigned char* __restrict__ hnq, const float* __restrict__ hs,
    const unsigned short* __restrict__ pS, const unsigned short* __restrict__ pN,
    float* __restrict__ hs2, unsigned char* __restrict__ hnq2,
    const float* __restrict__ mw1, const float* __restrict__ mb1,
    const float* __restrict__ mw2, const float* __restrict__ mb2,
    float* __restrict__ out) {
    __shared__ unsigned short sA[MLP ? 1 : 16 * 80];   // 16 nodes x 64 bf16, stride 80
    __shared__ float sW1[MLP ? HID * 32 : 1];
    __shared__ float sW2[MLP ? 32 : 1];
    __shared__ float sB1[MLP ? 32 : 1];
    __shared__ float sH[MLP ? 16 * 68 : 1];
    if (MLP) {
        for (int i = threadIdx.x; i < HID * 32; i += 256) sW1[i] = mw1[i];
        if (threadIdx.x < 32) { sW2[threadIdx.x] = mw2[threadIdx.x]; sB1[threadIdx.x] = mb1[threadIdx.x]; }
        __syncthreads();
    }
    int sn   = threadIdx.x >> 4;          // node slot within block, 0..15
    int r    = threadIdx.x & 15;          // 4B chunk of the 64B row
    int node = blockIdx.x * 16 + sn;      // grid = 3125 -> exactly N_NODES
    int beg  = pbeg[node];
    int dg   = rdeg[node];
    int nbat = (dg + 7) >> 3;
    const i32x4* ip = (const i32x4*)(csr + beg);
    unsigned r4 = (unsigned)(r * 4);

    f32x2 acc2[2];
    acc2[0] = (f32x2){0.f, 0.f};
    acc2[1] = (f32x2){0.f, 0.f};

#pragma unroll 2
    for (int t = 0; t < nbat; ++t) {
        i32x4 a = ip[2 * t];
        i32x4 b = ip[2 * t + 1];
        unsigned wv[8];
#pragma unroll
        for (int u = 0; u < 4; ++u)
            wv[u]     = *(const unsigned*)(hnq + (((unsigned)a[u] << 6) + r4));
#pragma unroll
        for (int u = 0; u < 4; ++u)
            wv[u + 4] = *(const unsigned*)(hnq + (((unsigned)b[u] << 6) + r4));
#pragma unroll
        for (int u = 0; u < 8; ++u) {
#if __has_builtin(__builtin_amdgcn_cvt_pk_f32_fp8)
            acc2[0] += __builtin_amdgcn_cvt_pk_f32_fp8((int)wv[u], false);
            acc2[1] += __builtin_amdgcn_cvt_pk_f32_fp8((int)wv[u], true);
#else
            acc2[0] += (f32x2){__builtin_amdgcn_cvt_f32_fp8((int)wv[u], 0),
                               __builtin_amdgcn_cvt_f32_fp8((int)wv[u], 1)};
            acc2[1] += (f32x2){__builtin_amdgcn_cvt_f32_fp8((int)wv[u], 2),
                               __builtin_amdgcn_cvt_f32_fp8((int)wv[u], 3)};
#endif
        }
    }

    float acc[4] = {acc2[0][0], acc2[0][1], acc2[1][0], acc2[1][1]};
    float invdeg = 1.0f / fmaxf((float)dg, 1.0f);
    f32x4 h = *(const f32x4*)(hs + (size_t)node * HID + r * 4);
    float v[4], ss = 0.f;
#pragma unroll
    for (int k = 0; k < 4; ++k) {
        v[k] = fmaxf(fmaf(acc[k], invdeg, h[k]), 0.f);
        ss += v[k] * v[k];
    }
    // reduce across the 16 r-lanes of this node (masks 1,2,4,8)
    ss += __shfl_xor(ss, 1, 64);
    ss += __shfl_xor(ss, 2, 64);
    ss += __shfl_xor(ss, 4, 64);
    ss += __shfl_xor(ss, 8, 64);
    float rs = 1.0f / (sqrtf(ss) + EPS);

    if constexpr (!MLP) {
        // stage normalized row as bf16 into LDS (A-operand of next GEMM)
        unsigned short* ap = &sA[sn * 80 + r * 4];
#pragma unroll
        for (int k = 0; k < 4; ++k) ap[k] = f2bf(v[k] * rs);
        __syncthreads();
        // dual GEMM: wave wv_ covers (mat = wv_>>1, t-pair = (wv_&1)*2)
        int lane = threadIdx.x & 63;
        int wv_  = threadIdx.x >> 6;
        int m    = lane & 15;
        int quad = lane >> 4;
        const short8* pB = (const short8*)((wv_ < 2) ? pS : pN);
        int t0 = (wv_ & 1) * 2;
        f32x4 gacc[2];
        gacc[0] = (f32x4){0.f, 0.f, 0.f, 0.f};
        gacc[1] = (f32x4){0.f, 0.f, 0.f, 0.f};
#pragma unroll
        for (int c = 0; c < 2; ++c) {
            short8 a = *(const short8*)&sA[m * 80 + quad * 8 + c * 32];
#pragma unroll
            for (int tt = 0; tt < 2; ++tt) {
                short8 b = pB[(c * 4 + t0 + tt) * 64 + lane];
                gacc[tt] = __builtin_amdgcn_mfma_f32_16x16x32_bf16(a, b, gacc[tt], 0, 0, 0);
            }
        }
        int row0 = blockIdx.x * 16 + quad * 4;
#pragma unroll
        for (int tt = 0; tt < 2; ++tt) {
            int col = (t0 + tt) * 16 + m;
#pragma unroll
            for (int rr = 0; rr < 4; ++rr) {
                size_t o = (size_t)(row0 + rr) * HID + col;
                if (wv_ < 2) hs2[o]  = gacc[tt][rr];
                else         hnq2[o] = f2fp8(gacc[tt][rr]);
            }
        }
    } else {
#pragma unroll
        for (int k = 0; k < 4; ++k) sH[sn * 68 + r * 4 + k] = v[k] * rs;
        __syncthreads();
        // per node: 16 threads x 2 columns of the 64x32 MLP
        int c0 = r * 2;
        float y0 = sB1[c0], y1 = sB1[c0 + 1];
        const float* hrow2 = &sH[sn * 68];
#pragma unroll 8
        for (int k = 0; k < HID; ++k) {
            float hv = hrow2[k];
            y0 = fmaf(hv, sW1[k * 32 + c0], y0);
            y1 = fmaf(hv, sW1[k * 32 + c0 + 1], y1);
        }
        float p = fmaxf(y0, 0.f) * sW2[c0] + fmaxf(y1, 0.f) * sW2[c0 + 1];
        p += __shfl_xor(p, 1, 64);
        p += __shfl_xor(p, 2, 64);
        p += __shfl_xor(p, 4, 64);
        p += __shfl_xor(p, 8, 64);
        if (r == 0) out[node] = 1.0f / (1.0f + __expf(-(p + mb2[0])));
    }
}

extern "C" void kernel_launch(void* const* d_in, const int* in_sizes, int n_in,
                              void* d_out, int out_size, void* d_ws, size_t ws_size,
                              hipStream_t stream) {
    const float* x   = (const float*)d_in[0];
    const int*   ei  = (const int*)d_in[1];
    const float* w0s = (const float*)d_in[2];
    const float* w0n = (const float*)d_in[3];
    const float* w1s = (const float*)d_in[4];
    const float* w1n = (const float*)d_in[5];
    const float* w2s = (const float*)d_in[6];
    const float* w2n = (const float*)d_in[7];
    const float* mw1 = (const float*)d_in[8];
    const float* mb1 = (const float*)d_in[9];
    const float* mw2 = (const float*)d_in[10];
    const float* mb2 = (const float*)d_in[11];
    float*       out = (float*)d_out;

    // ---- workspace layout ----
    int* deg     = (int*)d_ws;            // 50048 (zeroed)
    int* gcount  = deg + 50048;           // 64    (zeroed; slot 0 used)
    int* pbeg    = gcount + 64;           // 50048
    int* cursor  = pbeg + 50048;          // 50048
    int* csr     = cursor + 50048;        // 2,000,128 (padded total <= 1.95M)
    const size_t NH = (size_t)N_NODES * HID;
    float*          hsA  = (float*)(csr + 2000128);               // NH f32
    unsigned char*  hnqA = (unsigned char*)(hsA + NH);            // NH fp8 + 64B zero row
    float*          hsB  = (float*)(hnqA + NH + 64);              // NH f32
    unsigned char*  hnqB = (unsigned char*)(hsB + NH);            // NH fp8 + 64B zero row
    unsigned short* p0S = (unsigned short*)(hnqB + NH + 64);      // 128*64
    unsigned short* p0N = p0S + IN_DIM * HID;
    unsigned short* p1S = p0N + IN_DIM * HID;    // 64*64
    unsigned short* p1N = p1S + HID * HID;
    unsigned short* p2S = p1N + HID * HID;
    unsigned short* p2N = p2S + HID * HID;
    // total ~34 MB

    const int gemm0Grid = (N_NODES / 16 + 3) / 4; // 782
    const int nodeGrid  = N_NODES / 16;           // 3125

    zero_ws<<<SBLK + 1, 256, 0, stream>>>(deg);
    count_pack<<<CBLK + 8, 256, 0, stream>>>(
        ei, deg, w0s, w0n, w1s, w1n, w2s, w2n,
        p0S, p0N, p1S, p1N, p2S, p2N, hnqA, hnqB);
    scan_gemm0<<<SBLK + gemm0Grid, 256, 0, stream>>>(
        deg, pbeg, cursor, csr, gcount, x, p0S, p0N, hsA, hnqA);
    scatter_csr<<<CBLK, 256, 0, stream>>>(ei, cursor, csr);

    // ---- layer 0 aggregate + fused layer-1 GEMM ----
    agg_update<false><<<nodeGrid, 256, 0, stream>>>(
        pbeg, deg, csr, hnqA, hsA, p1S, p1N, hsB, hnqB,
        nullptr, nullptr, nullptr, nullptr, nullptr);

    // ---- layer 1 aggregate + fused layer-2 GEMM ----
    agg_update<false><<<nodeGrid, 256, 0, stream>>>(
        pbeg, deg, csr, hnqB, hsB, p2S, p2N, hsA, hnqA,
        nullptr, nullptr, nullptr, nullptr, nullptr);

    // ---- layer 2 aggregate + fused MLP head ----
    agg_update<true><<<nodeGrid, 256, 0, stream>>>(
        pbeg, deg, csr, hnqA, hsA, nullptr, nullptr, nullptr, nullptr,
        mw1, mb1, mw2, mb2, out);
}

// Round 9
// 213.244 us; speedup vs baseline: 8.5566x; 1.6896x over previous
//
#include <hip/hip_runtime.h>
#include <hip/hip_bf16.h>
#include <math.h>

#define N_NODES 50000
#define N_EDGES 1600000
#define IN_DIM  128
#define HID     64
#define EPB     8192   // edges per sort block
#define NBLK    196    // ceil(N_EDGES / EPB)
#define NB      391    // ceil(N_NODES / 128) buckets of 128 nodes
#define CAP     8192   // LDS staging capacity (edges/bucket; mean 4092)
#define PBKT    8192   // padded per-bucket arena in csr_pad (max ~5300 used)
static constexpr float EPS = 1e-6f;

typedef __attribute__((ext_vector_type(8))) short          short8;   // 8 bf16
typedef __attribute__((ext_vector_type(4))) int            i32x4;
typedef __attribute__((ext_vector_type(4))) float          f32x4;
typedef __attribute__((ext_vector_type(2))) float          f32x2;

__device__ __forceinline__ unsigned short f2bf(float f) {   // round-nearest-even
    union { float f; unsigned int i; } c; c.f = f;
    unsigned int r = c.i + 0x7FFFu + ((c.i >> 16) & 1u);
    return (unsigned short)(r >> 16);
}
__device__ __forceinline__ unsigned char f2fp8(float f) {   // OCP e4m3, HW cvt
    int p = __builtin_amdgcn_cvt_pk_fp8_f32(f, f, 0, false);
    return (unsigned char)(p & 0xff);
}

// ==== weight packing =========================================================

template <int K>
__device__ __forceinline__ void pack_body(const float* __restrict__ wS,
                                          const float* __restrict__ wN,
                                          unsigned short* __restrict__ pS,
                                          unsigned short* __restrict__ pN, int blk) {
    constexpr int NSLOT = (K / 32) * 4 * 64;
    int slot = blk * 256 + (int)threadIdx.x;
    if (slot >= NSLOT) return;
    int lane = slot & 63;
    int ct   = slot >> 6;
    int t    = ct & 3;
    int c    = ct >> 2;
    int m    = lane & 15;
    int quad = lane >> 4;
    int col  = t * 16 + m;
#pragma unroll
    for (int j = 0; j < 8; ++j) {
        int k = c * 32 + quad * 8 + j;
        pS[slot * 8 + j] = f2bf(wS[k * 64 + col]);
        pN[slot * 8 + j] = f2bf(wN[k * 64 + col]);
    }
}

// ==== CSR build: binned counting sort ========================================

// blocks 0..NBLK-1: per-block bucket histogram; blocks NBLK..NBLK+7: weight pack
// (also zeroes the sentinel rows at hnqA[N_NODES] / hnqB[N_NODES])
__global__ __launch_bounds__(256) void bucket_count_pack(
    const int* __restrict__ ei, int* __restrict__ blockCounts,
    const float* __restrict__ w0s, const float* __restrict__ w0n,
    const float* __restrict__ w1s, const float* __restrict__ w1n,
    const float* __restrict__ w2s, const float* __restrict__ w2n,
    unsigned short* __restrict__ p0S, unsigned short* __restrict__ p0N,
    unsigned short* __restrict__ p1S, unsigned short* __restrict__ p1N,
    unsigned short* __restrict__ p2S, unsigned short* __restrict__ p2N,
    unsigned char* __restrict__ hnqA, unsigned char* __restrict__ hnqB) {
    if (blockIdx.x >= NBLK) {
        int blk = blockIdx.x - NBLK;
        if (blk == 7) {
            if (threadIdx.x >= 128 && threadIdx.x < 144)
                ((unsigned int*)(hnqA + (size_t)N_NODES * HID))[threadIdx.x - 128] = 0u;
            if (threadIdx.x >= 144 && threadIdx.x < 160)
                ((unsigned int*)(hnqB + (size_t)N_NODES * HID))[threadIdx.x - 144] = 0u;
        }
        if (blk < 4)      pack_body<IN_DIM>(w0s, w0n, p0S, p0N, blk);
        else if (blk < 6) pack_body<HID>(w1s, w1n, p1S, p1N, blk - 4);
        else              pack_body<HID>(w2s, w2n, p2S, p2N, blk - 6);
        return;
    }
    __shared__ int hist[NB];
    for (int i = threadIdx.x; i < NB; i += 256) hist[i] = 0;
    __syncthreads();
    int base = blockIdx.x * EPB;
    int lim  = min(EPB, N_EDGES - base);
    for (int i = threadIdx.x; i < lim; i += 256)
        atomicAdd(&hist[ei[N_EDGES + base + i] >> 7], 1);
    __syncthreads();
    for (int b = threadIdx.x; b < NB; b += 256)
        blockCounts[blockIdx.x * NB + b] = hist[b];
}

// ==== dual GEMM body (layer 0 only) ==========================================
// hs = A@wS (fp32 out), hn = A@wN (fp8 e4m3 out)
template <int K, bool F32IN>
__device__ __forceinline__ void gemm_body(
    const void* __restrict__ Av,
    const unsigned short* __restrict__ pS,
    const unsigned short* __restrict__ pN,
    float* __restrict__ hs, unsigned char* __restrict__ hnq, int blk) {
    constexpr int NC = K / 32;
    int lane = threadIdx.x & 63;
    int wv   = threadIdx.x >> 6;
    int tile = blk * 4 + wv;
    if (tile >= N_NODES / 16) return;
    int m    = lane & 15;
    int quad = lane >> 4;

    const short8* pSf = (const short8*)pS;
    const short8* pNf = (const short8*)pN;

    f32x4 accS[4], accN[4];
#pragma unroll
    for (int t = 0; t < 4; ++t) {
        accS[t] = (f32x4){0.f, 0.f, 0.f, 0.f};
        accN[t] = (f32x4){0.f, 0.f, 0.f, 0.f};
    }
#pragma unroll
    for (int c = 0; c < NC; ++c) {
        short8 a;
        if constexpr (F32IN) {
            const float* Af = (const float*)Av + ((size_t)tile * 16 + m) * K + quad * 8 + c * 32;
            f32x4 a0 = *(const f32x4*)Af;
            f32x4 a1 = *(const f32x4*)(Af + 4);
#pragma unroll
            for (int k = 0; k < 4; ++k) a[k]     = (short)f2bf(a0[k]);
#pragma unroll
            for (int k = 0; k < 4; ++k) a[k + 4] = (short)f2bf(a1[k]);
        } else {
            const short8* Af = (const short8*)((const unsigned short*)Av +
                               ((size_t)tile * 16 + m) * K + quad * 8);
            a = Af[c * 4];
        }
#pragma unroll
        for (int t = 0; t < 4; ++t) {
            short8 bs = pSf[(c * 4 + t) * 64 + lane];
            short8 bn = pNf[(c * 4 + t) * 64 + lane];
            accS[t] = __builtin_amdgcn_mfma_f32_16x16x32_bf16(a, bs, accS[t], 0, 0, 0);
            accN[t] = __builtin_amdgcn_mfma_f32_16x16x32_bf16(a, bn, accN[t], 0, 0, 0);
        }
    }
    int row0 = tile * 16 + quad * 4;
#pragma unroll
    for (int t = 0; t < 4; ++t) {
#pragma unroll
        for (int r = 0; r < 4; ++r) {
            size_t o = (size_t)(row0 + r) * HID + t * 16 + m;
            hs[o]  = accS[t][r];
            hnq[o] = f2fp8(accN[t][r]);
        }
    }
}

// blocks 0..NB-1: col_sum; blocks NB.. : layer-0 GEMM (independent work overlap)
__global__ __launch_bounds__(256) void col_sum_gemm0(
    const int* __restrict__ blockCounts, int* __restrict__ totals,
    const float* __restrict__ x,
    const unsigned short* __restrict__ p0S, const unsigned short* __restrict__ p0N,
    float* __restrict__ hs, unsigned char* __restrict__ hnq) {
    if (blockIdx.x >= NB) {
        gemm_body<IN_DIM, true>(x, p0S, p0N, hs, hnq, blockIdx.x - NB);
        return;
    }
    __shared__ int ws[4];
    int b = blockIdx.x;
    int s = 0;
    for (int i = threadIdx.x; i < NBLK; i += 256) s += blockCounts[i * NB + b];
#pragma unroll
    for (int off = 32; off >= 1; off >>= 1) s += __shfl_xor(s, off, 64);
    if ((threadIdx.x & 63) == 0) ws[threadIdx.x >> 6] = s;
    __syncthreads();
    if (threadIdx.x == 0) totals[b] = ws[0] + ws[1] + ws[2] + ws[3];
}

// col_fix + integrated base scan
__global__ __launch_bounds__(256) void col_fix_base(int* __restrict__ blockCounts,
                                                    const int* __restrict__ totals,
                                                    int* __restrict__ bucketBase) {
    __shared__ int vals[NBLK];
    __shared__ int sbase;
    int b = blockIdx.x;
    for (int i = threadIdx.x; i < NBLK; i += 256) vals[i] = blockCounts[i * NB + b];
    if (threadIdx.x < 64) {   // wave 0: base_b = sum totals[0..b)
        int lane = threadIdx.x;
        int s = 0;
        for (int i = lane; i < b; i += 64) s += totals[i];
#pragma unroll
        for (int off = 32; off >= 1; off >>= 1) s += __shfl_xor(s, off, 64);
        if (lane == 0) {
            sbase = s;
            bucketBase[b] = s;
            if (b == NB - 1) bucketBase[NB] = s + totals[b];   // == N_EDGES
        }
    }
    __syncthreads();
    if (threadIdx.x < 64) {
        int lane  = threadIdx.x;
        int carry = sbase;
        for (int base = 0; base < NBLK; base += 64) {
            int i = base + lane;
            int v = (i < NBLK) ? vals[i] : 0;
            int incl = v;
#pragma unroll
            for (int off = 1; off < 64; off <<= 1) {
                int t = __shfl_up(incl, off, 64);
                if (lane >= off) incl += t;
            }
            if (i < NBLK) vals[i] = carry + incl - v;
            carry += __shfl(incl, 63, 64);
        }
    }
    __syncthreads();
    for (int i = threadIdx.x; i < NBLK; i += 256) blockCounts[i * NB + b] = vals[i];
}

// scatter edges into bucket-sorted order, packed (src<<7)|(dst&127)
__global__ __launch_bounds__(256) void bucket_scatter(const int* __restrict__ ei,
                                                      const int* __restrict__ blockCounts,
                                                      unsigned int* __restrict__ bucketPacked) {
    __shared__ int cur[NB];
    for (int b = threadIdx.x; b < NB; b += 256)
        cur[b] = blockCounts[blockIdx.x * NB + b];
    __syncthreads();
    int base = blockIdx.x * EPB;
    int lim  = min(EPB, N_EDGES - base);
    for (int i = threadIdx.x; i < lim; i += 256) {
        int s = ei[base + i];
        int d = ei[N_EDGES + base + i];
        int pos = atomicAdd(&cur[d >> 7], 1);
        bucketPacked[pos] = ((unsigned int)s << 7) | (unsigned int)(d & 127);
    }
}

// fused: per-bucket degree count -> PADDED in-bucket scan -> pbeg/rdeg ->
// sentinel fill -> local scatter into the padded per-bucket arena csr_pad.
// Each node's segment is padded to a multiple of 8 with sentinel N_NODES so
// the gather loop needs no per-edge tail masking.
__global__ __launch_bounds__(256) void node_scan_scatter_pad(
    const unsigned int* __restrict__ bucketPacked, const int* __restrict__ bucketBase,
    int* __restrict__ pbeg, int* __restrict__ rdeg, int* __restrict__ csr_pad) {
    __shared__ int cnt[128];
    __shared__ int half0;
    __shared__ unsigned int stage[CAP];
    int tid = threadIdx.x;
    if (tid < 128) cnt[tid] = 0;
    __syncthreads();
    int beg = bucketBase[blockIdx.x], end = bucketBase[blockIdx.x + 1];
    int n = end - beg;
    for (int i = tid; i < n; i += 256) {
        unsigned int e = bucketPacked[beg + i];
        if (i < CAP) stage[i] = e;
        atomicAdd(&cnt[e & 127], 1);
    }
    __syncthreads();
    int lane = tid & 63;
    int v    = (tid < 128) ? cnt[tid] : 0;   // raw degree of node tid
    int vp   = (v + 7) & ~7;                 // padded degree
    int incl = vp;
#pragma unroll
    for (int off = 1; off < 64; off <<= 1) {
        int t = __shfl_up(incl, off, 64);
        if (lane >= off) incl += t;
    }
    if (tid == 63) half0 = incl;
    __syncthreads();
    int start = blockIdx.x * PBKT + ((tid >= 64 && tid < 128) ? half0 : 0) + incl - vp;
    int node  = blockIdx.x * 128 + tid;
    if (tid < 128 && node < N_NODES) {
        pbeg[node] = start;
        rdeg[node] = v;
        for (int j = v; j < vp; ++j) csr_pad[start + j] = N_NODES;   // sentinels
        cnt[tid] = start;   // becomes the scatter cursor
    }
    __syncthreads();
    for (int i = tid; i < n; i += 256) {
        unsigned int e = (i < CAP) ? stage[i] : bucketPacked[beg + i];
        int pos = atomicAdd(&cnt[e & 127], 1);
        csr_pad[pos] = (int)(e >> 7);
    }
}

// ==== fused gather-aggregate + update + NEXT-LAYER dual GEMM (or MLP head) ===
// 4 nodes per wave, 16 lanes per node (sn = tid>>4, r = lane&15 -> 4B chunk).
// Maskless main loop (padded CSR): per edge = addr-fma + load + 2 cvt + 2 add.
// hs row is prefetched BEFORE the gather loop (no dependent stall at epilogue).
// !MLP: the block's 16 nodes form one GEMM tile. Normalized bf16 rows staged
// in LDS (stride 80 shorts, bank-spread), then the 4 waves each compute one
// (matrix, t-pair) quarter of the dual MFMA GEMM -> next layer's hs2/hnq2.
template <bool MLP>
__global__ __launch_bounds__(256) void agg_update(
    const int* __restrict__ pbeg, const int* __restrict__ rdeg,
    const int* __restrict__ csr_pad,
    const unsigned char* __restrict__ hnq, const float* __restrict__ hs,
    const unsigned short* __restrict__ pS, const unsigned short* __restrict__ pN,
    float* __restrict__ hs2, unsigned char* __restrict__ hnq2,
    const float* __restrict__ mw1, const float* __restrict__ mb1,
    const float* __restrict__ mw2, const float* __restrict__ mb2,
    float* __restrict__ out) {
    __shared__ unsigned short sA[MLP ? 1 : 16 * 80];   // 16 nodes x 64 bf16, stride 80
    __shared__ float sW1[MLP ? HID * 32 : 1];
    __shared__ float sW2[MLP ? 32 : 1];
    __shared__ float sB1[MLP ? 32 : 1];
    __shared__ float sH[MLP ? 16 * 68 : 1];
    if (MLP) {
        for (int i = threadIdx.x; i < HID * 32; i += 256) sW1[i] = mw1[i];
        if (threadIdx.x < 32) { sW2[threadIdx.x] = mw2[threadIdx.x]; sB1[threadIdx.x] = mb1[threadIdx.x]; }
        __syncthreads();
    }
    int sn   = threadIdx.x >> 4;          // node slot within block, 0..15
    int r    = threadIdx.x & 15;          // 4B chunk of the 64B row
    int node = blockIdx.x * 16 + sn;      // grid = 3125 -> exactly N_NODES
    int beg  = pbeg[node];
    int dg   = rdeg[node];
    f32x4 h  = *(const f32x4*)(hs + (size_t)node * HID + r * 4);   // prefetch
    int nbat = (dg + 7) >> 3;
    const i32x4* ip = (const i32x4*)(csr_pad + beg);
    unsigned r4 = (unsigned)(r * 4);

    f32x2 acc2[2];
    acc2[0] = (f32x2){0.f, 0.f};
    acc2[1] = (f32x2){0.f, 0.f};

#pragma unroll 2
    for (int t = 0; t < nbat; ++t) {
        i32x4 a = ip[2 * t];
        i32x4 b = ip[2 * t + 1];
        unsigned wv[8];
#pragma unroll
        for (int u = 0; u < 4; ++u)
            wv[u]     = *(const unsigned*)(hnq + (((unsigned)a[u] << 6) + r4));
#pragma unroll
        for (int u = 0; u < 4; ++u)
            wv[u + 4] = *(const unsigned*)(hnq + (((unsigned)b[u] << 6) + r4));
#pragma unroll
        for (int u = 0; u < 8; ++u) {
#if __has_builtin(__builtin_amdgcn_cvt_pk_f32_fp8)
            acc2[0] += __builtin_amdgcn_cvt_pk_f32_fp8((int)wv[u], false);
            acc2[1] += __builtin_amdgcn_cvt_pk_f32_fp8((int)wv[u], true);
#else
            acc2[0] += (f32x2){__builtin_amdgcn_cvt_f32_fp8((int)wv[u], 0),
                               __builtin_amdgcn_cvt_f32_fp8((int)wv[u], 1)};
            acc2[1] += (f32x2){__builtin_amdgcn_cvt_f32_fp8((int)wv[u], 2),
                               __builtin_amdgcn_cvt_f32_fp8((int)wv[u], 3)};
#endif
        }
    }

    float acc[4] = {acc2[0][0], acc2[0][1], acc2[1][0], acc2[1][1]};
    float invdeg = 1.0f / fmaxf((float)dg, 1.0f);
    float v[4], ss = 0.f;
#pragma unroll
    for (int k = 0; k < 4; ++k) {
        v[k] = fmaxf(fmaf(acc[k], invdeg, h[k]), 0.f);
        ss += v[k] * v[k];
    }
    // reduce across the 16 r-lanes of this node (masks 1,2,4,8)
    ss += __shfl_xor(ss, 1, 64);
    ss += __shfl_xor(ss, 2, 64);
    ss += __shfl_xor(ss, 4, 64);
    ss += __shfl_xor(ss, 8, 64);
    float rs = 1.0f / (sqrtf(ss) + EPS);

    if constexpr (!MLP) {
        // stage normalized row as bf16 into LDS (A-operand of next GEMM)
        unsigned short* ap = &sA[sn * 80 + r * 4];
#pragma unroll
        for (int k = 0; k < 4; ++k) ap[k] = f2bf(v[k] * rs);
        __syncthreads();
        // dual GEMM: wave wv_ covers (mat = wv_>>1, t-pair = (wv_&1)*2)
        int lane = threadIdx.x & 63;
        int wv_  = threadIdx.x >> 6;
        int m    = lane & 15;
        int quad = lane >> 4;
        const short8* pB = (const short8*)((wv_ < 2) ? pS : pN);
        int t0 = (wv_ & 1) * 2;
        f32x4 gacc[2];
        gacc[0] = (f32x4){0.f, 0.f, 0.f, 0.f};
        gacc[1] = (f32x4){0.f, 0.f, 0.f, 0.f};
#pragma unroll
        for (int c = 0; c < 2; ++c) {
            short8 a = *(const short8*)&sA[m * 80 + quad * 8 + c * 32];
#pragma unroll
            for (int tt = 0; tt < 2; ++tt) {
                short8 b = pB[(c * 4 + t0 + tt) * 64 + lane];
                gacc[tt] = __builtin_amdgcn_mfma_f32_16x16x32_bf16(a, b, gacc[tt], 0, 0, 0);
            }
        }
        int row0 = blockIdx.x * 16 + quad * 4;
#pragma unroll
        for (int tt = 0; tt < 2; ++tt) {
            int col = (t0 + tt) * 16 + m;
#pragma unroll
            for (int rr = 0; rr < 4; ++rr) {
                size_t o = (size_t)(row0 + rr) * HID + col;
                if (wv_ < 2) hs2[o]  = gacc[tt][rr];
                else         hnq2[o] = f2fp8(gacc[tt][rr]);
            }
        }
    } else {
#pragma unroll
        for (int k = 0; k < 4; ++k) sH[sn * 68 + r * 4 + k] = v[k] * rs;
        __syncthreads();
        // per node: 16 threads x 2 columns of the 64x32 MLP
        int c0 = r * 2;
        float y0 = sB1[c0], y1 = sB1[c0 + 1];
        const float* hrow2 = &sH[sn * 68];
#pragma unroll 8
        for (int k = 0; k < HID; ++k) {
            float hv = hrow2[k];
            y0 = fmaf(hv, sW1[k * 32 + c0], y0);
            y1 = fmaf(hv, sW1[k * 32 + c0 + 1], y1);
        }
        float p = fmaxf(y0, 0.f) * sW2[c0] + fmaxf(y1, 0.f) * sW2[c0 + 1];
        p += __shfl_xor(p, 1, 64);
        p += __shfl_xor(p, 2, 64);
        p += __shfl_xor(p, 4, 64);
        p += __shfl_xor(p, 8, 64);
        if (r == 0) out[node] = 1.0f / (1.0f + __expf(-(p + mb2[0])));
    }
}

extern "C" void kernel_launch(void* const* d_in, const int* in_sizes, int n_in,
                              void* d_out, int out_size, void* d_ws, size_t ws_size,
                              hipStream_t stream) {
    const float* x   = (const float*)d_in[0];
    const int*   ei  = (const int*)d_in[1];
    const float* w0s = (const float*)d_in[2];
    const float* w0n = (const float*)d_in[3];
    const float* w1s = (const float*)d_in[4];
    const float* w1n = (const float*)d_in[5];
    const float* w2s = (const float*)d_in[6];
    const float* w2n = (const float*)d_in[7];
    const float* mw1 = (const float*)d_in[8];
    const float* mb1 = (const float*)d_in[9];
    const float* mw2 = (const float*)d_in[10];
    const float* mb2 = (const float*)d_in[11];
    float*       out = (float*)d_out;

    // ---- workspace layout (all sections 16B aligned) ----
    int* pbeg        = (int*)d_ws;               // 50048
    int* rdeg        = pbeg + 50048;             // 50048
    int* blockCounts = rdeg + 50048;             // NBLK*NB = 76636 (pad 76800)
    int* bucketBase  = blockCounts + 76800;      // 512
    int* totals      = bucketBase + 512;         // 512
    unsigned int* bucketPacked = (unsigned int*)(totals + 512);   // 1.6M uint
    int* csr_pad     = (int*)(bucketPacked + N_EDGES);            // NB*PBKT = 3,203,072
    const size_t NH = (size_t)N_NODES * HID;
    float*          hsA  = (float*)(csr_pad + NB * PBKT);         // NH f32
    unsigned char*  hnqA = (unsigned char*)(hsA + NH);            // NH fp8 + 64B zero row
    float*          hsB  = (float*)(hnqA + NH + 64);              // NH f32
    unsigned char*  hnqB = (unsigned char*)(hsB + NH);            // NH fp8 + 64B zero row
    unsigned short* p0S = (unsigned short*)(hnqB + NH + 64);      // 128*64
    unsigned short* p0N = p0S + IN_DIM * HID;
    unsigned short* p1S = p0N + IN_DIM * HID;    // 64*64
    unsigned short* p1N = p1S + HID * HID;
    unsigned short* p2S = p1N + HID * HID;
    unsigned short* p2N = p2S + HID * HID;
    // total ~55 MB

    const int nodeGrid = N_NODES / 16;           // 3125 blocks: 16 nodes/block, 4 waves
    const int gemmGrid = (N_NODES / 16 + 3) / 4; // 782 (layer-0 GEMM only)

    // ---- CSR build + weight pack + layer-0 GEMM (packed into idle dispatches) ----
    bucket_count_pack<<<NBLK + 8, 256, 0, stream>>>(
        ei, blockCounts, w0s, w0n, w1s, w1n, w2s, w2n,
        p0S, p0N, p1S, p1N, p2S, p2N, hnqA, hnqB);
    col_sum_gemm0<<<NB + gemmGrid, 256, 0, stream>>>(
        blockCounts, totals, x, p0S, p0N, hsA, hnqA);
    col_fix_base<<<NB, 256, 0, stream>>>(blockCounts, totals, bucketBase);
    bucket_scatter<<<NBLK, 256, 0, stream>>>(ei, blockCounts, bucketPacked);
    node_scan_scatter_pad<<<NB, 256, 0, stream>>>(bucketPacked, bucketBase,
                                                  pbeg, rdeg, csr_pad);

    // ---- layer 0 aggregate + fused layer-1 GEMM ----
    agg_update<false><<<nodeGrid, 256, 0, stream>>>(
        pbeg, rdeg, csr_pad, hnqA, hsA, p1S, p1N, hsB, hnqB,
        nullptr, nullptr, nullptr, nullptr, nullptr);

    // ---- layer 1 aggregate + fused layer-2 GEMM ----
    agg_update<false><<<nodeGrid, 256, 0, stream>>>(
        pbeg, rdeg, csr_pad, hnqB, hsB, p2S, p2N, hsA, hnqA,
        nullptr, nullptr, nullptr, nullptr, nullptr);

    // ---- layer 2 aggregate + fused MLP head ----
    agg_update<true><<<nodeGrid, 256, 0, stream>>>(
        pbeg, rdeg, csr_pad, hnqA, hsA, nullptr, nullptr, nullptr, nullptr,
        mw1, mb1, mw2, mb2, out);
}

// Round 11
// 205.941 us; speedup vs baseline: 8.8600x; 1.0355x over previous
//
#include <hip/hip_runtime.h>
#include <hip/hip_bf16.h>
#include <math.h>

#define N_NODES 50000
#define N_EDGES 1600000
#define IN_DIM  128
#define HID     64
#define EPB     4096   // edges per sort block
#define NBLK    391    // ceil(N_EDGES / EPB)
#define NB      391    // ceil(N_NODES / 128) buckets of 128 nodes
#define CAP     8192   // LDS staging capacity (edges/bucket; mean 4092)
#define PBKT    8192   // padded per-bucket arena in csr_pad (max ~5300 used)
#define GEMM0G  782    // layer-0 GEMM blocks
static constexpr float EPS = 1e-6f;

typedef __attribute__((ext_vector_type(8))) short          short8;   // 8 bf16
typedef __attribute__((ext_vector_type(4))) int            i32x4;
typedef __attribute__((ext_vector_type(4))) float          f32x4;
typedef __attribute__((ext_vector_type(2))) float          f32x2;

__device__ __forceinline__ unsigned short f2bf(float f) {   // round-nearest-even
    union { float f; unsigned int i; } c; c.f = f;
    unsigned int r = c.i + 0x7FFFu + ((c.i >> 16) & 1u);
    return (unsigned short)(r >> 16);
}
__device__ __forceinline__ unsigned char f2fp8(float f) {   // OCP e4m3, HW cvt
    int p = __builtin_amdgcn_cvt_pk_fp8_f32(f, f, 0, false);
    return (unsigned char)(p & 0xff);
}

// ==== weight packing =========================================================

template <int K>
__device__ __forceinline__ void pack_body(const float* __restrict__ wS,
                                          const float* __restrict__ wN,
                                          unsigned short* __restrict__ pS,
                                          unsigned short* __restrict__ pN, int blk) {
    constexpr int NSLOT = (K / 32) * 4 * 64;
    int slot = blk * 256 + (int)threadIdx.x;
    if (slot >= NSLOT) return;
    int lane = slot & 63;
    int ct   = slot >> 6;
    int t    = ct & 3;
    int c    = ct >> 2;
    int m    = lane & 15;
    int quad = lane >> 4;
    int col  = t * 16 + m;
#pragma unroll
    for (int j = 0; j < 8; ++j) {
        int k = c * 32 + quad * 8 + j;
        pS[slot * 8 + j] = f2bf(wS[k * 64 + col]);
        pN[slot * 8 + j] = f2bf(wN[k * 64 + col]);
    }
}

// ==== dual GEMM body (layer 0) ===============================================
template <int K, bool F32IN>
__device__ __forceinline__ void gemm_body(
    const void* __restrict__ Av,
    const unsigned short* __restrict__ pS,
    const unsigned short* __restrict__ pN,
    float* __restrict__ hs, unsigned char* __restrict__ hnq, int blk) {
    constexpr int NC = K / 32;
    int lane = threadIdx.x & 63;
    int wv   = threadIdx.x >> 6;
    int tile = blk * 4 + wv;
    if (tile >= N_NODES / 16) return;
    int m    = lane & 15;
    int quad = lane >> 4;

    const short8* pSf = (const short8*)pS;
    const short8* pNf = (const short8*)pN;

    f32x4 accS[4], accN[4];
#pragma unroll
    for (int t = 0; t < 4; ++t) {
        accS[t] = (f32x4){0.f, 0.f, 0.f, 0.f};
        accN[t] = (f32x4){0.f, 0.f, 0.f, 0.f};
    }
#pragma unroll
    for (int c = 0; c < NC; ++c) {
        short8 a;
        if constexpr (F32IN) {
            const float* Af = (const float*)Av + ((size_t)tile * 16 + m) * K + quad * 8 + c * 32;
            f32x4 a0 = *(const f32x4*)Af;
            f32x4 a1 = *(const f32x4*)(Af + 4);
#pragma unroll
            for (int k = 0; k < 4; ++k) a[k]     = (short)f2bf(a0[k]);
#pragma unroll
            for (int k = 0; k < 4; ++k) a[k + 4] = (short)f2bf(a1[k]);
        } else {
            const short8* Af = (const short8*)((const unsigned short*)Av +
                               ((size_t)tile * 16 + m) * K + quad * 8);
            a = Af[c * 4];
        }
#pragma unroll
        for (int t = 0; t < 4; ++t) {
            short8 bs = pSf[(c * 4 + t) * 64 + lane];
            short8 bn = pNf[(c * 4 + t) * 64 + lane];
            accS[t] = __builtin_amdgcn_mfma_f32_16x16x32_bf16(a, bs, accS[t], 0, 0, 0);
            accN[t] = __builtin_amdgcn_mfma_f32_16x16x32_bf16(a, bn, accN[t], 0, 0, 0);
        }
    }
    int row0 = tile * 16 + quad * 4;
#pragma unroll
    for (int t = 0; t < 4; ++t) {
#pragma unroll
        for (int r = 0; r < 4; ++r) {
            size_t o = (size_t)(row0 + r) * HID + t * 16 + m;
            hs[o]  = accS[t][r];
            hnq[o] = f2fp8(accN[t][r]);
        }
    }
}

// ==== kernel 1: histogram count ∥ weight pack ================================
// blocks 0..NBLK-1: per-block bucket histogram; NBLK..NBLK+7: pack (blk 7 also
// zeroes sentinel rows + gcount).
__global__ __launch_bounds__(256) void bucket_count_pack(
    const int* __restrict__ ei, int* __restrict__ bc,
    const float* __restrict__ w0s, const float* __restrict__ w0n,
    const float* __restrict__ w1s, const float* __restrict__ w1n,
    const float* __restrict__ w2s, const float* __restrict__ w2n,
    unsigned short* __restrict__ p0S, unsigned short* __restrict__ p0N,
    unsigned short* __restrict__ p1S, unsigned short* __restrict__ p1N,
    unsigned short* __restrict__ p2S, unsigned short* __restrict__ p2N,
    unsigned char* __restrict__ hnqA, unsigned char* __restrict__ hnqB,
    int* __restrict__ gcount) {
    if (blockIdx.x >= NBLK) {
        int blk = blockIdx.x - NBLK;
        if (blk == 7) {
            if (threadIdx.x >= 128 && threadIdx.x < 144)
                ((unsigned int*)(hnqA + (size_t)N_NODES * HID))[threadIdx.x - 128] = 0u;
            if (threadIdx.x >= 144 && threadIdx.x < 160)
                ((unsigned int*)(hnqB + (size_t)N_NODES * HID))[threadIdx.x - 144] = 0u;
            if (threadIdx.x == 160) gcount[0] = 0;
        }
        if (blk < 4)      pack_body<IN_DIM>(w0s, w0n, p0S, p0N, blk);
        else if (blk < 6) pack_body<HID>(w1s, w1n, p1S, p1N, blk - 4);
        else              pack_body<HID>(w2s, w2n, p2S, p2N, blk - 6);
        return;
    }
    __shared__ int hist[NB];
    for (int i = threadIdx.x; i < NB; i += 256) hist[i] = 0;
    __syncthreads();
    int base = blockIdx.x * EPB;
    int lim  = min(EPB, N_EDGES - base);
    for (int i = threadIdx.x; i < lim; i += 256)
        atomicAdd(&hist[ei[N_EDGES + base + i] >> 7], 1);
    __syncthreads();
    for (int b = threadIdx.x; b < NB; b += 256)
        bc[blockIdx.x * NB + b] = hist[b];
}

// ==== kernel 2: fused col_sum + base-alloc + in-row prefix ∥ layer-0 GEMM ====
// block b < NB: total_b = sum of its bucket row; base_b = atomicAdd(gcount,
// total) (order-free allocation — nondeterministic bucket order, harmless);
// exclusive prefix with carry = base_b. blocks NB..: layer-0 GEMM (pack done
// in kernel 1, so the producer ordering is respected).
__global__ __launch_bounds__(256) void col_sumfix_gemm0(
    int* __restrict__ bc, int* __restrict__ bucketBase, int* __restrict__ bucketTot,
    int* __restrict__ gcount,
    const float* __restrict__ x,
    const unsigned short* __restrict__ p0S, const unsigned short* __restrict__ p0N,
    float* __restrict__ hs, unsigned char* __restrict__ hnq) {
    if (blockIdx.x >= NB) {
        gemm_body<IN_DIM, true>(x, p0S, p0N, hs, hnq, blockIdx.x - NB);
        return;
    }
    __shared__ int vals[NBLK];
    int b = blockIdx.x;
    for (int i = threadIdx.x; i < NBLK; i += 256) vals[i] = bc[i * NB + b];
    __syncthreads();
    if (threadIdx.x < 64) {
        int lane = threadIdx.x;
        int s = 0;
        for (int i = lane; i < NBLK; i += 64) s += vals[i];
#pragma unroll
        for (int off = 32; off >= 1; off >>= 1) s += __shfl_xor(s, off, 64);
        int base = 0;
        if (lane == 0) {
            base = atomicAdd(gcount, s);
            bucketBase[b] = base;
            bucketTot[b]  = s;
        }
        base = __shfl(base, 0, 64);
        int carry = base;
        for (int bs = 0; bs < NBLK; bs += 64) {
            int i = bs + lane;
            int v = (i < NBLK) ? vals[i] : 0;
            int incl = v;
#pragma unroll
            for (int off = 1; off < 64; off <<= 1) {
                int t = __shfl_up(incl, off, 64);
                if (lane >= off) incl += t;
            }
            if (i < NBLK) vals[i] = carry + incl - v;
            carry += __shfl(incl, 63, 64);
        }
    }
    __syncthreads();
    for (int i = threadIdx.x; i < NBLK; i += 256) bc[i * NB + b] = vals[i];
}

// ==== kernel 3: scatter edges into bucket-sorted order =======================
__global__ __launch_bounds__(256) void bucket_scatter(const int* __restrict__ ei,
                                                      const int* __restrict__ bc,
                                                      unsigned int* __restrict__ bucketPacked) {
    __shared__ int cur[NB];
    for (int b = threadIdx.x; b < NB; b += 256)
        cur[b] = bc[blockIdx.x * NB + b];
    __syncthreads();
    int base = blockIdx.x * EPB;
    int lim  = min(EPB, N_EDGES - base);
    for (int i = threadIdx.x; i < lim; i += 256) {
        int s = ei[base + i];
        int d = ei[N_EDGES + base + i];
        int pos = atomicAdd(&cur[d >> 7], 1);
        bucketPacked[pos] = ((unsigned int)s << 7) | (unsigned int)(d & 127);
    }
}

// ==== kernel 4: per-bucket degree count -> padded scan -> pbeg/rdeg ->
// sentinel fill -> local scatter into the padded per-bucket arena csr_pad.
__global__ __launch_bounds__(256) void node_scan_scatter_pad(
    const unsigned int* __restrict__ bucketPacked,
    const int* __restrict__ bucketBase, const int* __restrict__ bucketTot,
    int* __restrict__ pbeg, int* __restrict__ rdeg, int* __restrict__ csr_pad) {
    __shared__ int cnt[128];
    __shared__ int half0;
    __shared__ unsigned int stage[CAP];
    int tid = threadIdx.x;
    if (tid < 128) cnt[tid] = 0;
    __syncthreads();
    int beg = bucketBase[blockIdx.x];
    int n   = bucketTot[blockIdx.x];
    for (int i = tid; i < n; i += 256) {
        unsigned int e = bucketPacked[beg + i];
        if (i < CAP) stage[i] = e;
        atomicAdd(&cnt[e & 127], 1);
    }
    __syncthreads();
    int lane = tid & 63;
    int v    = (tid < 128) ? cnt[tid] : 0;   // raw degree of node tid
    int vp   = (v + 7) & ~7;                 // padded degree
    int incl = vp;
#pragma unroll
    for (int off = 1; off < 64; off <<= 1) {
        int t = __shfl_up(incl, off, 64);
        if (lane >= off) incl += t;
    }
    if (tid == 63) half0 = incl;
    __syncthreads();
    int start = blockIdx.x * PBKT + ((tid >= 64 && tid < 128) ? half0 : 0) + incl - vp;
    int node  = blockIdx.x * 128 + tid;
    if (tid < 128 && node < N_NODES) {
        pbeg[node] = start;
        rdeg[node] = v;
        for (int j = v; j < vp; ++j) csr_pad[start + j] = N_NODES;   // sentinels
        cnt[tid] = start;   // becomes the scatter cursor
    }
    __syncthreads();
    for (int i = tid; i < n; i += 256) {
        unsigned int e = (i < CAP) ? stage[i] : bucketPacked[beg + i];
        int pos = atomicAdd(&cnt[e & 127], 1);
        csr_pad[pos] = (int)(e >> 7);
    }
}

// ==== fused gather-aggregate + update + NEXT-LAYER dual GEMM (or MLP head) ===
// 4 nodes per wave, 16 lanes per node (sn = tid>>4, r = lane&15 -> 4B chunk).
// Maskless main loop (padded CSR); hs row prefetched before the gather loop.
// !MLP: the block's 16 nodes form one GEMM tile -> next layer's hs2/hnq2.
template <bool MLP>
__global__ __launch_bounds__(256) void agg_update(
    const int* __restrict__ pbeg, const int* __restrict__ rdeg,
    const int* __restrict__ csr_pad,
    const unsigned char* __restrict__ hnq, const float* __restrict__ hs,
    const unsigned short* __restrict__ pS, const unsigned short* __restrict__ pN,
    float* __restrict__ hs2, unsigned char* __restrict__ hnq2,
    const float* __restrict__ mw1, const float* __restrict__ mb1,
    const float* __restrict__ mw2, const float* __restrict__ mb2,
    float* __restrict__ out) {
    __shared__ unsigned short sA[MLP ? 1 : 16 * 80];   // 16 nodes x 64 bf16, stride 80
    __shared__ float sW1[MLP ? HID * 32 : 1];
    __shared__ float sW2[MLP ? 32 : 1];
    __shared__ float sB1[MLP ? 32 : 1];
    __shared__ float sH[MLP ? 16 * 68 : 1];
    if (MLP) {
        for (int i = threadIdx.x; i < HID * 32; i += 256) sW1[i] = mw1[i];
        if (threadIdx.x < 32) { sW2[threadIdx.x] = mw2[threadIdx.x]; sB1[threadIdx.x] = mb1[threadIdx.x]; }
        __syncthreads();
    }
    int sn   = threadIdx.x >> 4;          // node slot within block, 0..15
    int r    = threadIdx.x & 15;          // 4B chunk of the 64B row
    int node = blockIdx.x * 16 + sn;      // grid = 3125 -> exactly N_NODES
    int beg  = pbeg[node];
    int dg   = rdeg[node];
    f32x4 h  = *(const f32x4*)(hs + (size_t)node * HID + r * 4);   // prefetch
    int nbat = (dg + 7) >> 3;
    const i32x4* ip = (const i32x4*)(csr_pad + beg);
    unsigned r4 = (unsigned)(r * 4);

    f32x2 acc2[2];
    acc2[0] = (f32x2){0.f, 0.f};
    acc2[1] = (f32x2){0.f, 0.f};

#pragma unroll 2
    for (int t = 0; t < nbat; ++t) {
        i32x4 a = ip[2 * t];
        i32x4 b = ip[2 * t + 1];
        unsigned wv[8];
#pragma unroll
        for (int u = 0; u < 4; ++u)
            wv[u]     = *(const unsigned*)(hnq + (((unsigned)a[u] << 6) + r4));
#pragma unroll
        for (int u = 0; u < 4; ++u)
            wv[u + 4] = *(const unsigned*)(hnq + (((unsigned)b[u] << 6) + r4));
#pragma unroll
        for (int u = 0; u < 8; ++u) {
#if __has_builtin(__builtin_amdgcn_cvt_pk_f32_fp8)
            acc2[0] += __builtin_amdgcn_cvt_pk_f32_fp8((int)wv[u], false);
            acc2[1] += __builtin_amdgcn_cvt_pk_f32_fp8((int)wv[u], true);
#else
            acc2[0] += (f32x2){__builtin_amdgcn_cvt_f32_fp8((int)wv[u], 0),
                               __builtin_amdgcn_cvt_f32_fp8((int)wv[u], 1)};
            acc2[1] += (f32x2){__builtin_amdgcn_cvt_f32_fp8((int)wv[u], 2),
                               __builtin_amdgcn_cvt_f32_fp8((int)wv[u], 3)};
#endif
        }
    }

    float acc[4] = {acc2[0][0], acc2[0][1], acc2[1][0], acc2[1][1]};
    float invdeg = 1.0f / fmaxf((float)dg, 1.0f);
    float v[4], ss = 0.f;
#pragma unroll
    for (int k = 0; k < 4; ++k) {
        v[k] = fmaxf(fmaf(acc[k], invdeg, h[k]), 0.f);
        ss += v[k] * v[k];
    }
    // reduce across the 16 r-lanes of this node (masks 1,2,4,8)
    ss += __shfl_xor(ss, 1, 64);
    ss += __shfl_xor(ss, 2, 64);
    ss += __shfl_xor(ss, 4, 64);
    ss += __shfl_xor(ss, 8, 64);
    float rs = 1.0f / (sqrtf(ss) + EPS);

    if constexpr (!MLP) {
        // stage normalized row as bf16 into LDS (A-operand of next GEMM)
        unsigned short* ap = &sA[sn * 80 + r * 4];
#pragma unroll
        for (int k = 0; k < 4; ++k) ap[k] = f2bf(v[k] * rs);
        __syncthreads();
        // dual GEMM: wave wv_ covers (mat = wv_>>1, t-pair = (wv_&1)*2)
        int lane = threadIdx.x & 63;
        int wv_  = threadIdx.x >> 6;
        int m    = lane & 15;
        int quad = lane >> 4;
        const short8* pB = (const short8*)((wv_ < 2) ? pS : pN);
        int t0 = (wv_ & 1) * 2;
        f32x4 gacc[2];
        gacc[0] = (f32x4){0.f, 0.f, 0.f, 0.f};
        gacc[1] = (f32x4){0.f, 0.f, 0.f, 0.f};
#pragma unroll
        for (int c = 0; c < 2; ++c) {
            short8 a = *(const short8*)&sA[m * 80 + quad * 8 + c * 32];
#pragma unroll
            for (int tt = 0; tt < 2; ++tt) {
                short8 b = pB[(c * 4 + t0 + tt) * 64 + lane];
                gacc[tt] = __builtin_amdgcn_mfma_f32_16x16x32_bf16(a, b, gacc[tt], 0, 0, 0);
            }
        }
        int row0 = blockIdx.x * 16 + quad * 4;
#pragma unroll
        for (int tt = 0; tt < 2; ++tt) {
            int col = (t0 + tt) * 16 + m;
#pragma unroll
            for (int rr = 0; rr < 4; ++rr) {
                size_t o = (size_t)(row0 + rr) * HID + col;
                if (wv_ < 2) hs2[o]  = gacc[tt][rr];
                else         hnq2[o] = f2fp8(gacc[tt][rr]);
            }
        }
    } else {
#pragma unroll
        for (int k = 0; k < 4; ++k) sH[sn * 68 + r * 4 + k] = v[k] * rs;
        __syncthreads();
        // per node: 16 threads x 2 columns of the 64x32 MLP
        int c0 = r * 2;
        float y0 = sB1[c0], y1 = sB1[c0 + 1];
        const float* hrow2 = &sH[sn * 68];
#pragma unroll 8
        for (int k = 0; k < HID; ++k) {
            float hv = hrow2[k];
            y0 = fmaf(hv, sW1[k * 32 + c0], y0);
            y1 = fmaf(hv, sW1[k * 32 + c0 + 1], y1);
        }
        float p = fmaxf(y0, 0.f) * sW2[c0] + fmaxf(y1, 0.f) * sW2[c0 + 1];
        p += __shfl_xor(p, 1, 64);
        p += __shfl_xor(p, 2, 64);
        p += __shfl_xor(p, 4, 64);
        p += __shfl_xor(p, 8, 64);
        if (r == 0) out[node] = 1.0f / (1.0f + __expf(-(p + mb2[0])));
    }
}

extern "C" void kernel_launch(void* const* d_in, const int* in_sizes, int n_in,
                              void* d_out, int out_size, void* d_ws, size_t ws_size,
                              hipStream_t stream) {
    const float* x   = (const float*)d_in[0];
    const int*   ei  = (const int*)d_in[1];
    const float* w0s = (const float*)d_in[2];
    const float* w0n = (const float*)d_in[3];
    const float* w1s = (const float*)d_in[4];
    const float* w1n = (const float*)d_in[5];
    const float* w2s = (const float*)d_in[6];
    const float* w2n = (const float*)d_in[7];
    const float* mw1 = (const float*)d_in[8];
    const float* mb1 = (const float*)d_in[9];
    const float* mw2 = (const float*)d_in[10];
    const float* mb2 = (const float*)d_in[11];
    float*       out = (float*)d_out;

    // ---- workspace layout (all sections 16B aligned) ----
    int* pbeg        = (int*)d_ws;               // 50048
    int* rdeg        = pbeg + 50048;             // 50048
    int* bc          = rdeg + 50048;             // NBLK*NB = 152881 (pad 153600)
    int* bucketBase  = bc + 153600;              // 512
    int* bucketTot   = bucketBase + 512;         // 512
    int* gcount      = bucketTot + 512;          // 64
    unsigned int* bucketPacked = (unsigned int*)(gcount + 64);    // 1.6M uint
    int* csr_pad     = (int*)(bucketPacked + N_EDGES);            // NB*PBKT = 3,203,072
    const size_t NH = (size_t)N_NODES * HID;
    float*          hsA  = (float*)(csr_pad + NB * PBKT);         // NH f32
    unsigned char*  hnqA = (unsigned char*)(hsA + NH);            // NH fp8 + 64B zero row
    float*          hsB  = (float*)(hnqA + NH + 64);              // NH f32
    unsigned char*  hnqB = (unsigned char*)(hsB + NH);            // NH fp8 + 64B zero row
    unsigned short* p0S = (unsigned short*)(hnqB + NH + 64);      // 128*64
    unsigned short* p0N = p0S + IN_DIM * HID;
    unsigned short* p1S = p0N + IN_DIM * HID;    // 64*64
    unsigned short* p1N = p1S + HID * HID;
    unsigned short* p2S = p1N + HID * HID;
    unsigned short* p2N = p2S + HID * HID;
    // total ~55 MB

    const int nodeGrid = N_NODES / 16;           // 3125 blocks: 16 nodes/block, 4 waves

    // ---- build chain (4 dispatches; gemm0 overlapped with col_sumfix) ----
    bucket_count_pack<<<NBLK + 8, 256, 0, stream>>>(
        ei, bc, w0s, w0n, w1s, w1n, w2s, w2n,
        p0S, p0N, p1S, p1N, p2S, p2N, hnqA, hnqB, gcount);
    col_sumfix_gemm0<<<NB + GEMM0G, 256, 0, stream>>>(
        bc, bucketBase, bucketTot, gcount, x, p0S, p0N, hsA, hnqA);
    bucket_scatter<<<NBLK, 256, 0, stream>>>(ei, bc, bucketPacked);
    node_scan_scatter_pad<<<NB, 256, 0, stream>>>(bucketPacked, bucketBase, bucketTot,
                                                  pbeg, rdeg, csr_pad);

    // ---- layer 0 aggregate + fused layer-1 GEMM ----
    agg_update<false><<<nodeGrid, 256, 0, stream>>>(
        pbeg, rdeg, csr_pad, hnqA, hsA, p1S, p1N, hsB, hnqB,
        nullptr, nullptr, nullptr, nullptr, nullptr);

    // ---- layer 1 aggregate + fused layer-2 GEMM ----
    agg_update<false><<<nodeGrid, 256, 0, stream>>>(
        pbeg, rdeg, csr_pad, hnqB, hsB, p2S, p2N, hsA, hnqA,
        nullptr, nullptr, nullptr, nullptr, nullptr);

    // ---- layer 2 aggregate + fused MLP head ----
    agg_update<true><<<nodeGrid, 256, 0, stream>>>(
        pbeg, rdeg, csr_pad, hnqA, hsA, nullptr, nullptr, nullptr, nullptr,
        mw1, mb1, mw2, mb2, out);
}